// Round 11
// baseline (132.297 us; speedup 1.0000x reference)
//
#include <hip/hip_runtime.h>
#include <hip/hip_bf16.h>

// B=8192, N=2048 (GEMM reduce dim), K=64 (output cols), f32 in/out.
// res = 0.5*( ||x@v||^2 - sum_n x[n]^2 * s[n] ),  s[n] = sum_k v[n,k]^2.
// xv GEMM in bf16 hi/lo split (3 MFMAs; xl*vl dropped, rel err ~2^-17).
// R11 DIAGNOSTIC ROUND: fm_main reverted to exact R6 structure (no NT, no
// manual prefetch, no unroll) and launched TWICE (cold->d_out, warm->scratch)
// so both dispatches clear the ~41.5us ws-poison fills and appear in the
// rocprof top-5 WITH counters. Cold row = truth; warm-cold delta isolates
// memory-latency share. Costs ~+40us total this round; informs the fix.
#define B_ROWS 8192
#define N_DIM  2048
#define K_DIM  64

using frag_ab = __attribute__((ext_vector_type(8))) short;  // 8 bf16 = 4 VGPR
using frag_cd = __attribute__((ext_vector_type(4))) float;  // 4 f32

// ---- fused prep: block c owns v rows [32c, 32c+32) ----
// (1) pack those rows into MFMA-B hi/lo fragments (same sigma as A-side:
//     n = lane&15, k = (lane>>4)*8 + i), (2) s[n] = sum_k v[n,k]^2.
__global__ __launch_bounds__(256) void fm_prep(const float* __restrict__ v,
                                               unsigned short* __restrict__ vh,
                                               unsigned short* __restrict__ vl,
                                               float* __restrict__ s) {
    const int c = blockIdx.x;          // 32-row chunk of v (MFMA-k chunk)
    const int t = threadIdx.x >> 6;    // n-tile 0..3 (16 output-cols each)
    const int l = threadIdx.x & 63;
    const int kb = c * 32 + ((l >> 4) << 3);
    const int n  = t * 16 + (l & 15);
    frag_ab hv, lv;
    #pragma unroll
    for (int i = 0; i < 8; ++i) {
        float f = v[(size_t)(kb + i) * K_DIM + n];
        __hip_bfloat16 h = __float2bfloat16(f);          // RNE hi
        float fh = __bfloat162float(h);
        __hip_bfloat16 r = __float2bfloat16(f - fh);     // RNE lo
        hv[i] = (short)*reinterpret_cast<unsigned short*>(&h);
        lv[i] = (short)*reinterpret_cast<unsigned short*>(&r);
    }
    const size_t off = ((size_t)(c * 4 + t) * 64 + l) * 8;
    *reinterpret_cast<frag_ab*>(vh + off) = hv;   // coalesced 16B/lane
    *reinterpret_cast<frag_ab*>(vl + off) = lv;

    // s for the same 32 rows: wave t covers rows c*32 + t*8 .. +8
    #pragma unroll
    for (int j = 0; j < 8; ++j) {
        const int row = c * 32 + t * 8 + j;
        float val = v[(size_t)row * K_DIM + l];   // 64 cols <-> 64 lanes
        float sq = val * val;
        #pragma unroll
        for (int o = 1; o < 64; o <<= 1) sq += __shfl_xor(sq, o, 64);
        if (l == 0) s[row] = sq;
    }
}

// ---- main (exact R6 structure): 16 rows/block, 8 waves, wave w reduces
//      K-slice [w*256,(w+1)*256) ----
__global__ __launch_bounds__(512, 4) void fm_main(const float* __restrict__ x,
                                                  const float* __restrict__ s,
                                                  const unsigned short* __restrict__ vhp,
                                                  const unsigned short* __restrict__ vlp,
                                                  float* __restrict__ out) {
    __shared__ float lds_acc[8][16][65];   // pad 65: conflict-free scatter
    __shared__ float lds_ss[8][16];

    const int l   = threadIdx.x & 63;
    const int w   = __builtin_amdgcn_readfirstlane((int)(threadIdx.x >> 6));
    const int b0  = blockIdx.x * 16;
    const int row = l & 15;                // A-fragment M index
    const int kg  = l >> 4;                // lane k-group

    frag_cd acc[4];
    #pragma unroll
    for (int t = 0; t < 4; ++t) acc[t] = frag_cd{0.f, 0.f, 0.f, 0.f};
    float ssum = 0.f;

    const float* xrow = x + (size_t)(b0 + row) * N_DIM + kg * 8;
    const int c0 = w * 8;                  // global 32-k chunk base for this wave

    for (int c = 0; c < 8; ++c) {
        const int cc = c0 + c;
        const float4 xa = *(const float4*)(xrow + cc * 32);
        const float4 xb = *(const float4*)(xrow + cc * 32 + 4);
        const float4 sa = *(const float4*)(s + cc * 32 + kg * 8);
        const float4 sb = *(const float4*)(s + cc * 32 + kg * 8 + 4);
        const float xs[8] = {xa.x, xa.y, xa.z, xa.w, xb.x, xb.y, xb.z, xb.w};
        const float sv[8] = {sa.x, sa.y, sa.z, sa.w, sb.x, sb.y, sb.z, sb.w};
        frag_ab ah, al;
        #pragma unroll
        for (int i = 0; i < 8; ++i) {
            const float f = xs[i];
            __hip_bfloat16 h = __float2bfloat16(f);
            const float fh = __bfloat162float(h);
            __hip_bfloat16 r = __float2bfloat16(f - fh);
            ah[i] = (short)*reinterpret_cast<unsigned short*>(&h);
            al[i] = (short)*reinterpret_cast<unsigned short*>(&r);
            ssum = fmaf(f * f, sv[i], ssum);   // x^2*s rides the same loads
        }
        const unsigned short* ph = vhp + ((size_t)cc * 256 + l) * 8;
        const unsigned short* pl = vlp + ((size_t)cc * 256 + l) * 8;
        #pragma unroll
        for (int t = 0; t < 4; ++t) {
            const frag_ab bh = *(const frag_ab*)(ph + t * 512);  // L2 path
            const frag_ab bl = *(const frag_ab*)(pl + t * 512);
            acc[t] = __builtin_amdgcn_mfma_f32_16x16x32_bf16(ah, bh, acc[t], 0, 0, 0);
            acc[t] = __builtin_amdgcn_mfma_f32_16x16x32_bf16(al, bh, acc[t], 0, 0, 0);
            acc[t] = __builtin_amdgcn_mfma_f32_16x16x32_bf16(ah, bl, acc[t], 0, 0, 0);
        }
    }

    // ssum: lanes {r, r+16, r+32, r+48} hold row r partials
    ssum += __shfl_xor(ssum, 16, 64);
    ssum += __shfl_xor(ssum, 32, 64);
    if (l < 16) lds_ss[w][l] = ssum;
    // D layout (m89-verified): n = lane&15, m = (lane>>4)*4 + r
    #pragma unroll
    for (int t = 0; t < 4; ++t) {
        #pragma unroll
        for (int r = 0; r < 4; ++r)
            lds_acc[w][kg * 4 + r][t * 16 + row] = acc[t][r];
    }
    __syncthreads();

    #pragma unroll
    for (int rr = 0; rr < 2; ++rr) {
        const int m = w * 2 + rr;
        float tsum = 0.f;
        #pragma unroll
        for (int w2 = 0; w2 < 8; ++w2) tsum += lds_acc[w2][m][l];  // stride-1
        float q = tsum * tsum;
        #pragma unroll
        for (int off = 1; off < 64; off <<= 1) q += __shfl_xor(q, off, 64);
        if (l == 0) {
            float sst = 0.f;
            #pragma unroll
            for (int w2 = 0; w2 < 8; ++w2) sst += lds_ss[w2][m];
            out[b0 + m] = 0.5f * (q - sst);
        }
    }
}

extern "C" void kernel_launch(void* const* d_in, const int* in_sizes, int n_in,
                              void* d_out, int out_size, void* d_ws, size_t ws_size,
                              hipStream_t stream) {
    const float* x = (const float*)d_in[0];   // [8192, 2048] f32
    const float* v = (const float*)d_in[1];   // [2048, 64]  f32
    float* out = (float*)d_out;               // [8192] f32
    // workspace layout: s (8KB) | vh (256KB) | vl (256KB) | ... | out2 @1MB
    float* s = (float*)d_ws;
    unsigned short* vh = (unsigned short*)((char*)d_ws + 8192);
    unsigned short* vl = (unsigned short*)((char*)d_ws + 8192 + 262144);
    float* out2 = (float*)((char*)d_ws + (1 << 20));   // diagnostic sink

    fm_prep<<<dim3(64), dim3(256), 0, stream>>>(v, vh, vl, s);
    // Launch 1 (COLD, scored): clean counter row for the real kernel.
    fm_main<<<dim3(B_ROWS / 16), dim3(512), 0, stream>>>(x, s, vh, vl, out);
    // Launch 2 (WARM, diagnostic): x now L3-resident; warm-vs-cold delta
    // separates memory-latency/BW share from issue/VALU share.
    fm_main<<<dim3(B_ROWS / 16), dim3(512), 0, stream>>>(x, s, vh, vl, out2);
}

// Round 13
// 127.795 us; speedup vs baseline: 1.0352x; 1.0352x over previous
//
#include <hip/hip_runtime.h>
#include <hip/hip_bf16.h>

// B=8192, N=2048 (GEMM reduce dim), K=64 (output cols), f32 in/out.
// res = 0.5*( ||x@v||^2 - sum_n x[n]^2 * s[n] ),  s[n] = sum_k v[n,k]^2.
// xv GEMM in bf16 hi/lo split (3 MFMAs; xl*vl dropped, rel err ~2^-17).
// R12 DIAGNOSTIC: fm_main runs the full computation TWICE inside one
// dispatch (#pragma unroll 1 rep loop: rep0 -> out, rep1 -> ws sink) so the
// dispatch (~55us) clears the ~41us ws-poison fills and appears in rocprof
// top-5 WITH counters. Compute structure otherwise identical to R6.
#define B_ROWS 8192
#define N_DIM  2048
#define K_DIM  64

using frag_ab = __attribute__((ext_vector_type(8))) short;  // 8 bf16 = 4 VGPR
using frag_cd = __attribute__((ext_vector_type(4))) float;  // 4 f32

// ---- fused prep: block c owns v rows [32c, 32c+32) ----
__global__ __launch_bounds__(256) void fm_prep(const float* __restrict__ v,
                                               unsigned short* __restrict__ vh,
                                               unsigned short* __restrict__ vl,
                                               float* __restrict__ s) {
    const int c = blockIdx.x;          // 32-row chunk of v (MFMA-k chunk)
    const int t = threadIdx.x >> 6;    // n-tile 0..3 (16 output-cols each)
    const int l = threadIdx.x & 63;
    const int kb = c * 32 + ((l >> 4) << 3);
    const int n  = t * 16 + (l & 15);
    frag_ab hv, lv;
    #pragma unroll
    for (int i = 0; i < 8; ++i) {
        float f = v[(size_t)(kb + i) * K_DIM + n];
        __hip_bfloat16 h = __float2bfloat16(f);          // RNE hi
        float fh = __bfloat162float(h);
        __hip_bfloat16 r = __float2bfloat16(f - fh);     // RNE lo
        hv[i] = (short)*reinterpret_cast<unsigned short*>(&h);
        lv[i] = (short)*reinterpret_cast<unsigned short*>(&r);
    }
    const size_t off = ((size_t)(c * 4 + t) * 64 + l) * 8;
    *reinterpret_cast<frag_ab*>(vh + off) = hv;   // coalesced 16B/lane
    *reinterpret_cast<frag_ab*>(vl + off) = lv;

    #pragma unroll
    for (int j = 0; j < 8; ++j) {
        const int row = c * 32 + t * 8 + j;
        float val = v[(size_t)row * K_DIM + l];   // 64 cols <-> 64 lanes
        float sq = val * val;
        #pragma unroll
        for (int o = 1; o < 64; o <<= 1) sq += __shfl_xor(sq, o, 64);
        if (l == 0) s[row] = sq;
    }
}

// ---- main (R6 structure, x2 internal repeat for counter visibility) ----
__global__ __launch_bounds__(512, 4) void fm_main(const float* __restrict__ x,
                                                  const float* __restrict__ s,
                                                  const unsigned short* __restrict__ vhp,
                                                  const unsigned short* __restrict__ vlp,
                                                  float* __restrict__ out,
                                                  float* __restrict__ out2) {
    __shared__ float lds_acc[8][16][65];   // pad 65: conflict-free scatter
    __shared__ float lds_ss[8][16];

    const int l   = threadIdx.x & 63;
    const int w   = __builtin_amdgcn_readfirstlane((int)(threadIdx.x >> 6));
    const int b0  = blockIdx.x * 16;
    const int row = l & 15;                // A-fragment M index
    const int kg  = l >> 4;                // lane k-group

    const float* xrow = x + (size_t)(b0 + row) * N_DIM + kg * 8;
    const int c0 = w * 8;                  // global 32-k chunk base for this wave

    #pragma unroll 1                       // body EXECUTES twice: no cross-rep CSE
    for (int rep = 0; rep < 2; ++rep) {
        float* const target = rep ? out2 : out;

        frag_cd acc[4];
        #pragma unroll
        for (int t = 0; t < 4; ++t) acc[t] = frag_cd{0.f, 0.f, 0.f, 0.f};
        float ssum = 0.f;

        for (int c = 0; c < 8; ++c) {
            const int cc = c0 + c;
            const float4 xa = *(const float4*)(xrow + cc * 32);
            const float4 xb = *(const float4*)(xrow + cc * 32 + 4);
            const float4 sa = *(const float4*)(s + cc * 32 + kg * 8);
            const float4 sb = *(const float4*)(s + cc * 32 + kg * 8 + 4);
            const float xs[8] = {xa.x, xa.y, xa.z, xa.w, xb.x, xb.y, xb.z, xb.w};
            const float sv[8] = {sa.x, sa.y, sa.z, sa.w, sb.x, sb.y, sb.z, sb.w};
            frag_ab ah, al;
            #pragma unroll
            for (int i = 0; i < 8; ++i) {
                const float f = xs[i];
                __hip_bfloat16 h = __float2bfloat16(f);
                const float fh = __bfloat162float(h);
                __hip_bfloat16 r = __float2bfloat16(f - fh);
                ah[i] = (short)*reinterpret_cast<unsigned short*>(&h);
                al[i] = (short)*reinterpret_cast<unsigned short*>(&r);
                ssum = fmaf(f * f, sv[i], ssum);   // x^2*s rides the same loads
            }
            const unsigned short* ph = vhp + ((size_t)cc * 256 + l) * 8;
            const unsigned short* pl = vlp + ((size_t)cc * 256 + l) * 8;
            #pragma unroll
            for (int t = 0; t < 4; ++t) {
                const frag_ab bh = *(const frag_ab*)(ph + t * 512);  // L2 path
                const frag_ab bl = *(const frag_ab*)(pl + t * 512);
                acc[t] = __builtin_amdgcn_mfma_f32_16x16x32_bf16(ah, bh, acc[t], 0, 0, 0);
                acc[t] = __builtin_amdgcn_mfma_f32_16x16x32_bf16(al, bh, acc[t], 0, 0, 0);
                acc[t] = __builtin_amdgcn_mfma_f32_16x16x32_bf16(ah, bl, acc[t], 0, 0, 0);
            }
        }

        // ssum: lanes {r, r+16, r+32, r+48} hold row r partials
        ssum += __shfl_xor(ssum, 16, 64);
        ssum += __shfl_xor(ssum, 32, 64);
        if (l < 16) lds_ss[w][l] = ssum;
        // D layout (m89-verified): n = lane&15, m = (lane>>4)*4 + r
        #pragma unroll
        for (int t = 0; t < 4; ++t) {
            #pragma unroll
            for (int r = 0; r < 4; ++r)
                lds_acc[w][kg * 4 + r][t * 16 + row] = acc[t][r];
        }
        __syncthreads();

        #pragma unroll
        for (int rr = 0; rr < 2; ++rr) {
            const int m = w * 2 + rr;
            float tsum = 0.f;
            #pragma unroll
            for (int w2 = 0; w2 < 8; ++w2) tsum += lds_acc[w2][m][l];  // stride-1
            float q = tsum * tsum;
            #pragma unroll
            for (int off = 1; off < 64; off <<= 1) q += __shfl_xor(q, off, 64);
            if (l == 0) {
                float sst = 0.f;
                #pragma unroll
                for (int w2 = 0; w2 < 8; ++w2) sst += lds_ss[w2][m];
                target[b0 + m] = 0.5f * (q - sst);
            }
        }
        __syncthreads();   // protect lds_acc before next rep's writes
    }
}

extern "C" void kernel_launch(void* const* d_in, const int* in_sizes, int n_in,
                              void* d_out, int out_size, void* d_ws, size_t ws_size,
                              hipStream_t stream) {
    const float* x = (const float*)d_in[0];   // [8192, 2048] f32
    const float* v = (const float*)d_in[1];   // [2048, 64]  f32
    float* out = (float*)d_out;               // [8192] f32
    // workspace layout: s (8KB) | vh (256KB) | vl (256KB) | ... | sink @1MB
    float* s = (float*)d_ws;
    unsigned short* vh = (unsigned short*)((char*)d_ws + 8192);
    unsigned short* vl = (unsigned short*)((char*)d_ws + 8192 + 262144);
    float* out2 = (float*)((char*)d_ws + (1 << 20));   // diagnostic sink

    fm_prep<<<dim3(64), dim3(256), 0, stream>>>(v, vh, vl, s);
    fm_main<<<dim3(B_ROWS / 16), dim3(512), 0, stream>>>(x, s, vh, vl, out, out2);
}

// Round 14
// 111.428 us; speedup vs baseline: 1.1873x; 1.1469x over previous
//
#include <hip/hip_runtime.h>
#include <hip/hip_bf16.h>

// B=8192, N=2048 (GEMM reduce dim), K=64 (output cols), f32 in/out.
// res = 0.5*( ||x@v||^2 - sum_n x[n]^2 * s[n] ),  s[n] = sum_k v[n,k]^2.
// xv GEMM in bf16 hi/lo split (3 MFMAs; xl*vl dropped, rel err ~2^-17).
// R14: R13 counters showed latency-bound (MfmaUtil 8.5 / VALUBusy 12 /
// hbm 16% / Occ 35 — all low; L3-warm pass barely faster). Fix: hoist all
// 16 x-loads per wave BEFORE the compute loop (16 outstanding 16B loads/wave
// ~= the MLP needed for BW-bound), static unroll throughout. x2 repeat
// dropped; readout = total dur_us (overhead ~65-68us + prep ~4us calibrated).
#define B_ROWS 8192
#define N_DIM  2048
#define K_DIM  64

using frag_ab = __attribute__((ext_vector_type(8))) short;  // 8 bf16 = 4 VGPR
using frag_cd = __attribute__((ext_vector_type(4))) float;  // 4 f32
using f32x4   = __attribute__((ext_vector_type(4))) float;

__device__ inline f32x4 ld4(const float* p) {
    return *reinterpret_cast<const f32x4*>(p);
}

// ---- fused prep: block c owns v rows [32c, 32c+32) ----
__global__ __launch_bounds__(256) void fm_prep(const float* __restrict__ v,
                                               unsigned short* __restrict__ vh,
                                               unsigned short* __restrict__ vl,
                                               float* __restrict__ s) {
    const int c = blockIdx.x;          // 32-row chunk of v (MFMA-k chunk)
    const int t = threadIdx.x >> 6;    // n-tile 0..3 (16 output-cols each)
    const int l = threadIdx.x & 63;
    const int kb = c * 32 + ((l >> 4) << 3);
    const int n  = t * 16 + (l & 15);
    frag_ab hv, lv;
    #pragma unroll
    for (int i = 0; i < 8; ++i) {
        float f = v[(size_t)(kb + i) * K_DIM + n];
        __hip_bfloat16 h = __float2bfloat16(f);          // RNE hi
        float fh = __bfloat162float(h);
        __hip_bfloat16 r = __float2bfloat16(f - fh);     // RNE lo
        hv[i] = (short)*reinterpret_cast<unsigned short*>(&h);
        lv[i] = (short)*reinterpret_cast<unsigned short*>(&r);
    }
    const size_t off = ((size_t)(c * 4 + t) * 64 + l) * 8;
    *reinterpret_cast<frag_ab*>(vh + off) = hv;   // coalesced 16B/lane
    *reinterpret_cast<frag_ab*>(vl + off) = lv;

    #pragma unroll
    for (int j = 0; j < 8; ++j) {
        const int row = c * 32 + t * 8 + j;
        float val = v[(size_t)row * K_DIM + l];   // 64 cols <-> 64 lanes
        float sq = val * val;
        #pragma unroll
        for (int o = 1; o < 64; o <<= 1) sq += __shfl_xor(sq, o, 64);
        if (l == 0) s[row] = sq;
    }
}

// ---- main: 16 rows/block, 8 waves, wave w reduces K-slice [w*256,(w+1)*256)
//      All 16 x-loads issued up-front for MLP; compute drains them in order.
__global__ __launch_bounds__(512, 4) void fm_main(const float* __restrict__ x,
                                                  const float* __restrict__ s,
                                                  const unsigned short* __restrict__ vhp,
                                                  const unsigned short* __restrict__ vlp,
                                                  float* __restrict__ out) {
    __shared__ float lds_acc[8][16][65];   // pad 65: conflict-free scatter
    __shared__ float lds_ss[8][16];

    const int l   = threadIdx.x & 63;
    const int w   = __builtin_amdgcn_readfirstlane((int)(threadIdx.x >> 6));
    const int b0  = blockIdx.x * 16;
    const int row = l & 15;                // A-fragment M index
    const int kg  = l >> 4;                // lane k-group

    const float* xrow = x + (size_t)(b0 + row) * N_DIM + kg * 8;
    const int c0 = w * 8;                  // global 32-k chunk base for this wave

    // ---- MLP phase: 16 independent global loads in flight per wave ----
    f32x4 xa[8], xb[8];                    // 64 VGPR, static-indexed only
    #pragma unroll
    for (int c = 0; c < 8; ++c) {
        xa[c] = ld4(xrow + (c0 + c) * 32);
        xb[c] = ld4(xrow + (c0 + c) * 32 + 4);
    }

    frag_cd acc[4];
    #pragma unroll
    for (int t = 0; t < 4; ++t) acc[t] = frag_cd{0.f, 0.f, 0.f, 0.f};
    float ssum = 0.f;

    #pragma unroll
    for (int c = 0; c < 8; ++c) {
        const int cc = c0 + c;
        const f32x4 sa = ld4(s + cc * 32 + kg * 8);      // L1-hot after chunk 0
        const f32x4 sb = ld4(s + cc * 32 + kg * 8 + 4);
        frag_ab ah, al;
        #pragma unroll
        for (int i = 0; i < 8; ++i) {
            const float f  = (i < 4) ? xa[c][i] : xb[c][i - 4];
            const float sv = (i < 4) ? sa[i]    : sb[i - 4];
            __hip_bfloat16 h = __float2bfloat16(f);
            const float fh = __bfloat162float(h);
            __hip_bfloat16 r = __float2bfloat16(f - fh);
            ah[i] = (short)*reinterpret_cast<unsigned short*>(&h);
            al[i] = (short)*reinterpret_cast<unsigned short*>(&r);
            ssum = fmaf(f * f, sv, ssum);   // x^2*s rides the same loads
        }
        const unsigned short* ph = vhp + ((size_t)cc * 256 + l) * 8;
        const unsigned short* pl = vlp + ((size_t)cc * 256 + l) * 8;
        #pragma unroll
        for (int t = 0; t < 4; ++t) {
            const frag_ab bh = *(const frag_ab*)(ph + t * 512);  // L2 path
            const frag_ab bl = *(const frag_ab*)(pl + t * 512);
            acc[t] = __builtin_amdgcn_mfma_f32_16x16x32_bf16(ah, bh, acc[t], 0, 0, 0);
            acc[t] = __builtin_amdgcn_mfma_f32_16x16x32_bf16(al, bh, acc[t], 0, 0, 0);
            acc[t] = __builtin_amdgcn_mfma_f32_16x16x32_bf16(ah, bl, acc[t], 0, 0, 0);
        }
    }

    // ssum: lanes {r, r+16, r+32, r+48} hold row r partials
    ssum += __shfl_xor(ssum, 16, 64);
    ssum += __shfl_xor(ssum, 32, 64);
    if (l < 16) lds_ss[w][l] = ssum;
    // D layout (m89-verified): n = lane&15, m = (lane>>4)*4 + r
    #pragma unroll
    for (int t = 0; t < 4; ++t) {
        #pragma unroll
        for (int r = 0; r < 4; ++r)
            lds_acc[w][kg * 4 + r][t * 16 + row] = acc[t][r];
    }
    __syncthreads();

    #pragma unroll
    for (int rr = 0; rr < 2; ++rr) {
        const int m = w * 2 + rr;
        float tsum = 0.f;
        #pragma unroll
        for (int w2 = 0; w2 < 8; ++w2) tsum += lds_acc[w2][m][l];  // stride-1
        float q = tsum * tsum;
        #pragma unroll
        for (int off = 1; off < 64; off <<= 1) q += __shfl_xor(q, off, 64);
        if (l == 0) {
            float sst = 0.f;
            #pragma unroll
            for (int w2 = 0; w2 < 8; ++w2) sst += lds_ss[w2][m];
            out[b0 + m] = 0.5f * (q - sst);
        }
    }
}

extern "C" void kernel_launch(void* const* d_in, const int* in_sizes, int n_in,
                              void* d_out, int out_size, void* d_ws, size_t ws_size,
                              hipStream_t stream) {
    const float* x = (const float*)d_in[0];   // [8192, 2048] f32
    const float* v = (const float*)d_in[1];   // [2048, 64]  f32
    float* out = (float*)d_out;               // [8192] f32
    // workspace: s (8KB) | vh (256KB) | vl (256KB)
    float* s = (float*)d_ws;
    unsigned short* vh = (unsigned short*)((char*)d_ws + 8192);
    unsigned short* vl = (unsigned short*)((char*)d_ws + 8192 + 262144);

    fm_prep<<<dim3(64), dim3(256), 0, stream>>>(v, vh, vl, s);
    fm_main<<<dim3(B_ROWS / 16), dim3(512), 0, stream>>>(x, s, vh, vl, out);
}